// Round 4
// baseline (1713.403 us; speedup 1.0000x reference)
//
#include <hip/hip_runtime.h>
#include <cstdint>
#include <cstddef>

// Problem constants: B=64, T=512, D=256, H=512
#define T_STEPS 512
#define D_DIM 256
#define H_DIM 512
#define B_SZ 64

// rnn_scan7 = proven scan3 structure (4 col-groups x 128 cols, grid 256,
// bid = r + 64*cg so the quartet {r, r+64, r+128, r+192} is %8-identical ->
// same XCD under the measured blockIdx->XCD mapping) + DUAL-PATH exchange:
//   zfast: plain write-back store (write-through L1 -> lands in XCD L2) and
//          sc0 poll (L1-bypass, L2-served)      -> ~200cy RT if same-XCD
//   zslow: relaxed AGENT-scope store/load       -> always correct (~3000cy)
// Consumers fast-poll with a cap, then go STICKY slow. Correctness never
// depends on WG->XCD placement (tag-guarded single-writer packets; kernel
// dispatch boundaries invalidate caches so no cross-iteration staleness).
// Round-1 retry rationale: that attempt was killed by a w[128] VGPR spill
// (92<128) + 4x packet volume, not by the idea; grid=256 is 1 WG/CU, so
// __launch_bounds__(512,1) lifts the 128-VGPR target harmlessly.
#define NCG 4
#define CGW (H_DIM / NCG)   // 128
#define NTH 512
#define POLL_CAP 1024       // one-time burn if fast path is structurally dead

// d_ws layout: zfast u64[64][2][512] = 512 KB, then zslow same = 512 KB.
// 0xAAAAAAAA poison never equals a tag in 1..512; ws re-poisoned per iter.

// ---------------------------------------------------------------------------
// Kernel 1: xproj = inputs @ Wx + bias  ->  d_out  [B*T, H]   (unchanged)
// ---------------------------------------------------------------------------
#define BM 64
#define BN 128
#define BK 32

__global__ __launch_bounds__(256)
void xproj_gemm(const float* __restrict__ A, const float* __restrict__ Bm,
                const float* __restrict__ bias, float* __restrict__ C,
                int M, int N, int K) {
    __shared__ float As[BK][BM];
    __shared__ float Bs[BK][BN];

    const int tid = threadIdx.x;
    const int tx = tid & 15;
    const int ty = tid >> 4;
    const int row0 = blockIdx.y * BM;
    const int col0 = blockIdx.x * BN;

    float acc[4][8];
    #pragma unroll
    for (int i = 0; i < 4; ++i)
        #pragma unroll
        for (int j = 0; j < 8; ++j) acc[i][j] = 0.0f;

    for (int kt = 0; kt < K; kt += BK) {
        #pragma unroll
        for (int i = 0; i < 2; ++i) {
            int q  = tid + i * 256;
            int m  = q >> 3;
            int k4 = (q & 7) << 2;
            float4 v = *(const float4*)&A[(size_t)(row0 + m) * K + kt + k4];
            As[k4 + 0][m] = v.x; As[k4 + 1][m] = v.y;
            As[k4 + 2][m] = v.z; As[k4 + 3][m] = v.w;
        }
        #pragma unroll
        for (int i = 0; i < 4; ++i) {
            int q  = tid + i * 256;
            int kk = q >> 5;
            int n4 = (q & 31) << 2;
            *(float4*)&Bs[kk][n4] = *(const float4*)&Bm[(size_t)(kt + kk) * N + col0 + n4];
        }
        __syncthreads();
        #pragma unroll
        for (int k = 0; k < BK; ++k) {
            float4 a  = *(const float4*)&As[k][ty << 2];
            float4 b0 = *(const float4*)&Bs[k][tx << 2];
            float4 b1 = *(const float4*)&Bs[k][(tx << 2) + 64];
            float av[4] = {a.x, a.y, a.z, a.w};
            float bv[8] = {b0.x, b0.y, b0.z, b0.w, b1.x, b1.y, b1.z, b1.w};
            #pragma unroll
            for (int i = 0; i < 4; ++i)
                #pragma unroll
                for (int j = 0; j < 8; ++j)
                    acc[i][j] = fmaf(av[i], bv[j], acc[i][j]);
        }
        __syncthreads();
    }

    float bv0[4], bv1[4];
    #pragma unroll
    for (int j = 0; j < 4; ++j) {
        bv0[j] = bias[col0 + (tx << 2) + j];
        bv1[j] = bias[col0 + (tx << 2) + 64 + j];
    }
    #pragma unroll
    for (int i = 0; i < 4; ++i) {
        int r = row0 + (ty << 2) + i;
        float4 o0 = make_float4(acc[i][0] + bv0[0], acc[i][1] + bv0[1],
                                acc[i][2] + bv0[2], acc[i][3] + bv0[3]);
        float4 o1 = make_float4(acc[i][4] + bv1[0], acc[i][5] + bv1[1],
                                acc[i][6] + bv1[2], acc[i][7] + bv1[3]);
        *(float4*)&C[(size_t)r * N + col0 + (tx << 2)]      = o0;
        *(float4*)&C[(size_t)r * N + col0 + (tx << 2) + 64] = o1;
    }
}

// ---------------------------------------------------------------------------
__device__ __forceinline__ float tanh_fast(float x) {
    float ax = fabsf(x);
    float e  = __expf(2.0f * ax);
    float t  = 1.0f - 2.0f / (e + 1.0f);
    return copysignf(t, x);
}

// ---------------------------------------------------------------------------
// Kernel 2: scan3 body + dual-path exchange. fast_ok gates the fast path at
// launch (0 => byte-identical behavior to the proven scan3 on zslow).
// ---------------------------------------------------------------------------
__global__ __launch_bounds__(NTH, 1)
void rnn_scan7(const float* __restrict__ Wh, const float* __restrict__ h0,
               const float* __restrict__ gamma, const float* __restrict__ beta,
               float* __restrict__ out,
               unsigned long long* __restrict__ zfast,
               unsigned long long* __restrict__ zslow,
               int fast_ok) {
    const int r   = blockIdx.x & (B_SZ - 1);   // row; quartet shares r
    const int cg  = blockIdx.x >> 6;           // 0..3 (stride 64 -> same XCD)
    const int tid = threadIdx.x;               // 0..511
    const int c   = tid & (CGW - 1);           // 0..127
    const int kc  = tid >> 7;                  // 0..3 (wave-uniform)

    __shared__ float h_s[H_DIM];
    __shared__ float part_s[NCG][CGW];
    __shared__ float wred_s[16];

    // Wh register slice: w[j] = Wh[kc*128 + j][cg*128 + c]
    float w[128];
    #pragma unroll
    for (int j = 0; j < 128; ++j)
        w[j] = Wh[(size_t)(kc * 128 + j) * H_DIM + cg * CGW + c];

    h_s[tid] = h0[r * H_DIM + tid];
    const float g_own = gamma[tid];
    const float b_own = beta[tid];
    float* outrow = out + (size_t)r * T_STEPS * H_DIM;
    unsigned long long* zfrow0 = zfast + (size_t)(r * 2) * H_DIM;
    unsigned long long* zsrow0 = zslow + (size_t)(r * 2) * H_DIM;

    int fastmode = fast_ok;                    // per-thread sticky
    float xp_next = 0.0f;
    if (tid < CGW)
        xp_next = __builtin_nontemporal_load(&outrow[cg * CGW + tid]);
    __syncthreads();

    for (int t = 0; t < T_STEPS; ++t) {
        const size_t par = (size_t)(t & 1) * H_DIM;
        unsigned long long* zfrow = zfrow0 + par;
        unsigned long long* zsrow = zsrow0 + par;
        const unsigned int tag = (unsigned int)(t + 1);
        const float xp = xp_next;

        // partial z for own slice: 4 independent FMA chains (scan3 order)
        float acc = 0.0f;
        {
            const float4* h4 = (const float4*)&h_s[kc * 128];
            float a0 = 0.0f, a1 = 0.0f, a2 = 0.0f, a3 = 0.0f;
            #pragma unroll
            for (int j4 = 0; j4 < 32; ++j4) {
                float4 hv = h4[j4];
                a0 = fmaf(w[4 * j4 + 0], hv.x, a0);
                a1 = fmaf(w[4 * j4 + 1], hv.y, a1);
                a2 = fmaf(w[4 * j4 + 2], hv.z, a2);
                a3 = fmaf(w[4 * j4 + 3], hv.w, a3);
            }
            acc = (a0 + a1) + (a2 + a3);
        }
        part_s[kc][c] = acc;
        __syncthreads();                                   // barrier A

        // producers: combine partials, publish the SAME packet on both paths
        if (tid < CGW) {
            float z = xp + part_s[0][tid] + part_s[1][tid]
                         + part_s[2][tid] + part_s[3][tid];
            unsigned long long pkt =
                ((unsigned long long)tag << 32) | (unsigned long long)__float_as_uint(z);
            // plain write-back store: write-through L1 -> visible in XCD L2
            __hip_atomic_store(&zfrow[cg * CGW + tid], pkt,
                               __ATOMIC_RELAXED, __HIP_MEMORY_SCOPE_WORKGROUP);
            // agent-scope mirror: the always-correct path (scan3 protocol)
            __hip_atomic_store(&zsrow[cg * CGW + tid], pkt,
                               __ATOMIC_RELAXED, __HIP_MEMORY_SCOPE_AGENT);
        }

        // prefetch next xp while the publish drains
        if (tid < CGW && t + 1 < T_STEPS)
            xp_next = __builtin_nontemporal_load(
                &outrow[(size_t)(t + 1) * H_DIM + cg * CGW + tid]);

        // poll global column `tid`: fast (sc0 / L2) with cap, sticky fallback
        unsigned long long pkt = 0;
        bool got = false;
        if (fastmode) {
            const unsigned long long* fa = &zfrow[tid];
            #pragma unroll 1
            for (int it = 0; it < POLL_CAP; ++it) {
                unsigned long long v;
                asm volatile("global_load_dwordx2 %0, %1, off sc0\n\t"
                             "s_waitcnt vmcnt(0)"
                             : "=v"(v) : "v"(fa) : "memory");
                if ((unsigned)(v >> 32) == tag) { pkt = v; got = true; break; }
            }
            if (!got) fastmode = 0;            // structurally dead -> sticky
        }
        if (!got) {
            do {
                pkt = __hip_atomic_load(&zsrow[tid], __ATOMIC_RELAXED,
                                        __HIP_MEMORY_SCOPE_AGENT);
            } while ((unsigned int)(pkt >> 32) != tag);
        }
        float z = __uint_as_float((unsigned int)pkt);

        // LN stats over 512: identical fold to scan3
        float s = z, q = z * z;
        #pragma unroll
        for (int o = 32; o > 0; o >>= 1) {
            s += __shfl_down(s, o, 64);
            q += __shfl_down(q, o, 64);
        }
        const int wid = tid >> 6;
        if ((tid & 63) == 0) { wred_s[wid] = s; wred_s[8 + wid] = q; }
        __syncthreads();                                   // barrier B
        float S = 0.0f, Q = 0.0f;
        #pragma unroll
        for (int i = 0; i < 8; ++i) { S += wred_s[i]; Q += wred_s[8 + i]; }
        float mean = S * (1.0f / H_DIM);
        float var  = Q * (1.0f / H_DIM) - mean * mean;
        float rstd = rsqrtf(var + 1e-3f);                  // keras LN eps

        float hn = tanh_fast((z - mean) * rstd * g_own + b_own);
        if (kc == cg) outrow[t * H_DIM + tid] = hn;        // own slice store
        h_s[tid] = hn;            // all h_s reads ended before barrier A
        __syncthreads();                                   // barrier C
    }
}

// ---------------------------------------------------------------------------
extern "C" void kernel_launch(void* const* d_in, const int* in_sizes, int n_in,
                              void* d_out, int out_size, void* d_ws, size_t ws_size,
                              hipStream_t stream) {
    const float* inputs = (const float*)d_in[0];  // [B,T,D]
    const float* h0     = (const float*)d_in[1];  // [B,H]
    const float* Wx     = (const float*)d_in[2];  // [D,H]
    const float* Wh     = (const float*)d_in[3];  // [H,H]
    const float* bias   = (const float*)d_in[4];  // [H]
    const float* gamma  = (const float*)d_in[5];  // [H]
    const float* beta   = (const float*)d_in[6];  // [H]
    float* out = (float*)d_out;                   // [B,T,H]

    const int M = B_SZ * T_STEPS;                 // 32768
    dim3 g1(H_DIM / BN, M / BM);                  // (4, 512)
    xproj_gemm<<<g1, 256, 0, stream>>>(inputs, Wx, bias, out, M, H_DIM, D_DIM);

    const size_t zwords = (size_t)B_SZ * 2 * H_DIM;        // 64K u64 = 512 KB
    unsigned long long* zbase = (unsigned long long*)d_ws;
    if (ws_size >= 2 * zwords * sizeof(unsigned long long)) {
        // dual-path: zfast | zslow
        rnn_scan7<<<B_SZ * NCG, NTH, 0, stream>>>(Wh, h0, gamma, beta, out,
                                                  zbase, zbase + zwords, 1);
    } else {
        // degenerate: single buffer, fast path disabled (== proven scan3)
        rnn_scan7<<<B_SZ * NCG, NTH, 0, stream>>>(Wh, h0, gamma, beta, out,
                                                  zbase, zbase, 0);
    }
}